// Round 3
// baseline (435.697 us; speedup 1.0000x reference)
//
#include <hip/hip_runtime.h>
#include <hip/hip_bf16.h>

#define B_ 32
#define T_ 512
#define F_ 9
#define H_ 64
#define P_ 84
#define LE_ 510
#define LBL_ 10

struct CombT { int c[P_][3]; };
__host__ __device__ constexpr CombT make_combs() {
    CombT t{}; int n = 0;
    for (int a = 0; a < F_; ++a)
        for (int b = a + 1; b < F_; ++b)
            for (int c = b + 1; c < F_; ++c) { t.c[n][0] = a; t.c[n][1] = b; t.c[n][2] = c; ++n; }
    return t;
}
constexpr CombT COMB_H = make_combs();   // constexpr: folds at compile time under full unroll

// ---------------------------------------------------------------------------
// Kernel A: A[h][f*3+k] = sum_p va_w1[p] * sum_i [comb[p][i]==f] w[p,h,i,k]
//           Abias[h]    = va_b1[h] + sum_p va_w1[p]*conv_b[p,h]
// ---------------------------------------------------------------------------
__global__ __launch_bounds__(256) void precomp_kernel(
    const float* __restrict__ conv_w, const float* __restrict__ conv_b,
    const float* __restrict__ va_w1, const float* __restrict__ va_b1,
    float* __restrict__ A, float* __restrict__ Abias)
{
    __shared__ float sacc[256][28];
    int tid = threadIdx.x;
    int h = tid >> 2, q = tid & 3;            // 64 h  x  4 p-quarters
    for (int j = 0; j < 28; ++j) sacc[tid][j] = 0.f;
    for (int p = q * 21; p < (q + 1) * 21; ++p) {
        float w1 = va_w1[p];
        sacc[tid][27] += w1 * conv_b[p * H_ + h];
        const float* wp = conv_w + p * (H_ * 9) + h * 9;
        for (int i = 0; i < 3; ++i) {
            int f = COMB_H.c[p][i];
            for (int k = 0; k < 3; ++k) sacc[tid][f * 3 + k] += w1 * wp[i * 3 + k];
        }
    }
    __syncthreads();
    if (q == 0) {
        for (int j = 0; j < 27; ++j)
            A[h * 27 + j] = sacc[tid][j] + sacc[tid + 1][j] + sacc[tid + 2][j] + sacc[tid + 3][j];
        Abias[h] = va_b1[h] + sacc[tid][27] + sacc[tid + 1][27] + sacc[tid + 2][27] + sacc[tid + 3][27];
    }
}

// ---------------------------------------------------------------------------
// attn_kernel: per (ltile, b), 1024 threads (16 waves), lane = l.
// t1 (via A) -> t2 -> softmax -> store aw[b,lt,p,l] (normalized weights).
// ---------------------------------------------------------------------------
__global__ __launch_bounds__(1024) void attn_kernel(
    const float* __restrict__ x,
    const float* __restrict__ va_w2, const float* __restrict__ va_b2,
    const float* __restrict__ A, const float* __restrict__ Abias,
    float* __restrict__ aw)
{
    __shared__ float xs[66 * 9];
    __shared__ float t1s[64][65];       // banks (ln+h)%32: conflict-free
    __shared__ float t2s[64][85];       // banks (21*ln+p)%32: conflict-free

    const int b = blockIdx.y;
    const int lt = blockIdx.x;
    const int l0 = lt * 64;
    const int tid = threadIdx.x;
    const int ln = tid & 63;
    const int wv = tid >> 6;            // 0..15

    int maxidx = (T_ - l0) * F_; if (maxidx > 66 * F_) maxidx = 66 * F_;
    for (int i = tid; i < 66 * F_; i += 1024)
        xs[i] = (i < maxidx) ? x[b * (T_ * F_) + l0 * F_ + i] : 0.f;
    __syncthreads();

    // per-lane x window (static indices only)
    float xw[27];
#pragma unroll
    for (int k = 0; k < 3; ++k)
#pragma unroll
        for (int f = 0; f < F_; ++f) xw[k * 9 + f] = xs[(ln + k) * F_ + f];

    // t1: wave wv covers h = wv*4 .. wv*4+3
#pragma unroll
    for (int hh = 0; hh < 4; ++hh) {
        int h = wv * 4 + hh;
        const float* Ah = A + h * 27;
        float s = Abias[h];
#pragma unroll
        for (int f = 0; f < F_; ++f)
#pragma unroll
            for (int k = 0; k < 3; ++k) s = fmaf(xw[k * 9 + f], Ah[f * 3 + k], s);
        t1s[ln][h] = fmaxf(s, 0.f);
    }
    __syncthreads();

    // t2: wave wv covers a p-slice (first 4 waves: 6, rest: 5  -> 84 total)
    const int cnt = (wv < 4) ? 6 : 5;
    const int p0 = (wv < 4) ? wv * 6 : 24 + (wv - 4) * 5;
    {
        float t2acc[6];
#pragma unroll
        for (int j = 0; j < 6; ++j) t2acc[j] = (j < cnt) ? va_b2[p0 + j] : 0.f;
        for (int h = 0; h < H_; ++h) {
            float tv = t1s[ln][h];
            const float* w2h = va_w2 + h * P_ + p0;
#pragma unroll
            for (int j = 0; j < 6; ++j)
                if (j < cnt) t2acc[j] = fmaf(tv, w2h[j], t2acc[j]);
        }
#pragma unroll
        for (int j = 0; j < 6; ++j)
            if (j < cnt) t2s[ln][p0 + j] = fmaxf(t2acc[j], 0.f);
    }
    __syncthreads();

    // softmax params over own row (duplicated across waves; cheap)
    float mx = -1e30f;
    for (int p = 0; p < P_; ++p) mx = fmaxf(mx, t2s[ln][p]);
    float sum = 0.f;
    for (int p = 0; p < P_; ++p) sum += __expf(t2s[ln][p] - mx);
    float inv = 1.f / sum;

    // store normalized weights for own p-slice: aw[((b*8+lt)*84+p)*64 + ln]
    const int awbase = (b * 8 + lt) * P_;
#pragma unroll
    for (int j = 0; j < 6; ++j)
        if (j < cnt)
            aw[(awbase + p0 + j) * 64 + ln] = __expf(t2s[ln][p0 + j] - mx) * inv;
}

// ---------------------------------------------------------------------------
// passB_kernel: grid (ltile 8, b 32, hgrp 8), 256 threads (4 waves).
// Weights for the block's 8 h's staged in LDS (padded 12/row for float4
// reads); x window in registers (static combo indices via full p-unroll);
// aw read coalesced from global.  Each wave: 2 h's x 64 l's.
// ---------------------------------------------------------------------------
__global__ __launch_bounds__(256, 4) void passB_kernel(
    const float* __restrict__ x,
    const float* __restrict__ conv_w, const float* __restrict__ conv_b,
    const float* __restrict__ aw,
    float* __restrict__ v)
{
    __shared__ float xs[66 * 9];            // 2376 B
    __shared__ float ws_w[P_ * 8 * 12];     // 32256 B  (padded 9 -> 12)
    __shared__ float ws_b[P_ * 8];          // 2688 B

    const int lt = blockIdx.x;
    const int b = blockIdx.y;
    const int z = blockIdx.z;
    const int l0 = lt * 64;
    const int tid = threadIdx.x;
    const int ln = tid & 63;
    const int wv = tid >> 6;                // 0..3
    const int hh0 = wv * 2;                 // local h pair

    // ---- stage x rows ----
    int maxidx = (T_ - l0) * F_; if (maxidx > 66 * F_) maxidx = 66 * F_;
    for (int i = tid; i < 66 * F_; i += 256)
        xs[i] = (i < maxidx) ? x[b * (T_ * F_) + l0 * F_ + i] : 0.f;
    // ---- stage conv weights for h = z*8 .. z*8+7 (pad 9->12) ----
    for (int i = tid; i < P_ * 72; i += 256) {
        int p = i / 72, rr = i - p * 72;
        int hh = rr / 9, r = rr - hh * 9;
        ws_w[(p * 8 + hh) * 12 + r] = conv_w[p * (H_ * 9) + z * 72 + rr];
    }
    for (int i = tid; i < P_ * 8; i += 256) {
        int p = i >> 3, hh = i & 7;
        ws_b[i] = conv_b[p * H_ + z * 8 + hh];
    }
    __syncthreads();

    int valid = LE_ - l0; if (valid > 64) valid = 64;

    float xw[27];
#pragma unroll
    for (int k = 0; k < 3; ++k)
#pragma unroll
        for (int f = 0; f < F_; ++f) xw[k * 9 + f] = xs[(ln + k) * F_ + f];

    float acc0 = 0.f, acc1 = 0.f;
    const float* awp = aw + (b * 8 + lt) * (P_ * 64) + ln;

#pragma unroll
    for (int p = 0; p < P_; ++p) {
        const int f0 = COMB_H.c[p][0];      // compile-time after unroll
        const int f1 = COMB_H.c[p][1];
        const int f2 = COMB_H.c[p][2];
        float ap = awp[p * 64];

        const float4* w0 = reinterpret_cast<const float4*>(&ws_w[(p * 8 + hh0) * 12]);
        const float4* w1 = reinterpret_cast<const float4*>(&ws_w[(p * 8 + hh0 + 1) * 12]);
        float4 a0 = w0[0], a1 = w0[1];
        float  a2 = ws_w[(p * 8 + hh0) * 12 + 8];
        float4 b0 = w1[0], b1 = w1[1];
        float  b2 = ws_w[(p * 8 + hh0 + 1) * 12 + 8];

        float cv0 = ws_b[p * 8 + hh0];
        float cv1 = ws_b[p * 8 + hh0 + 1];
        // taps: [i0k0 i0k1 i0k2 i1k0] [i1k1 i1k2 i2k0 i2k1] [i2k2]
        cv0 = fmaf(a0.x, xw[0 * 9 + f0], cv0);
        cv0 = fmaf(a0.y, xw[1 * 9 + f0], cv0);
        cv0 = fmaf(a0.z, xw[2 * 9 + f0], cv0);
        cv0 = fmaf(a0.w, xw[0 * 9 + f1], cv0);
        cv0 = fmaf(a1.x, xw[1 * 9 + f1], cv0);
        cv0 = fmaf(a1.y, xw[2 * 9 + f1], cv0);
        cv0 = fmaf(a1.z, xw[0 * 9 + f2], cv0);
        cv0 = fmaf(a1.w, xw[1 * 9 + f2], cv0);
        cv0 = fmaf(a2,   xw[2 * 9 + f2], cv0);
        cv1 = fmaf(b0.x, xw[0 * 9 + f0], cv1);
        cv1 = fmaf(b0.y, xw[1 * 9 + f0], cv1);
        cv1 = fmaf(b0.z, xw[2 * 9 + f0], cv1);
        cv1 = fmaf(b0.w, xw[0 * 9 + f1], cv1);
        cv1 = fmaf(b1.x, xw[1 * 9 + f1], cv1);
        cv1 = fmaf(b1.y, xw[2 * 9 + f1], cv1);
        cv1 = fmaf(b1.z, xw[0 * 9 + f2], cv1);
        cv1 = fmaf(b1.w, xw[1 * 9 + f2], cv1);
        cv1 = fmaf(b2,   xw[2 * 9 + f2], cv1);

        acc0 = fmaf(ap, cv0, acc0);
        acc1 = fmaf(ap, cv1, acc1);
    }

    if (ln < valid) {
        const int h0 = z * 8 + hh0;
        v[(b * H_ + h0 + 0) * LE_ + l0 + ln] = acc0;
        v[(b * H_ + h0 + 1) * LE_ + l0 + ln] = acc1;
    }
}

// ---------------------------------------------------------------------------
// Kernel 2: temporal attention + FC.  one block per b.
// ---------------------------------------------------------------------------
__global__ __launch_bounds__(256) void ta_kernel(
    const float* __restrict__ v,
    const float* __restrict__ ta_w1, const float* __restrict__ ta_b1,
    const float* __restrict__ ta_w2, const float* __restrict__ ta_b2,
    const float* __restrict__ fc_w, const float* __restrict__ fc_b,
    float* __restrict__ out)
{
    __shared__ float u1s[64];
    __shared__ float attns[512];
    __shared__ float red[256];
    __shared__ float zs[64];

    const int b = blockIdx.x;
    const int tid = threadIdx.x;
    const int h = tid >> 2, q = tid & 3;
    const int lbeg = q * 128;
    const int lend = (lbeg + 128 < LE_) ? lbeg + 128 : LE_;
    const float* vb = v + (b * H_ + h) * LE_;

    {
        float s = 0.f;
        for (int l = lbeg; l < lend; ++l) s = fmaf(vb[l], ta_w1[l], s);
        red[tid] = s;
    }
    __syncthreads();
    if (tid < 64)
        u1s[tid] = fmaxf(ta_b1[tid] + red[tid * 4] + red[tid * 4 + 1] + red[tid * 4 + 2] + red[tid * 4 + 3], 0.f);
    __syncthreads();

    for (int l = tid; l < LE_; l += 256) {
        float s = ta_b2[l];
        for (int hx = 0; hx < H_; ++hx) s = fmaf(u1s[hx], ta_w2[hx * LE_ + l], s);
        attns[l] = fmaxf(s, 0.f);
    }
    __syncthreads();

    float m = -1e30f;
    for (int l = tid; l < LE_; l += 256) m = fmaxf(m, attns[l]);
    red[tid] = m; __syncthreads();
    for (int s = 128; s > 0; s >>= 1) { if (tid < s) red[tid] = fmaxf(red[tid], red[tid + s]); __syncthreads(); }
    m = red[0]; __syncthreads();

    float ssum = 0.f;
    for (int l = tid; l < LE_; l += 256) { float e = __expf(attns[l] - m); attns[l] = e; ssum += e; }
    red[tid] = ssum; __syncthreads();
    for (int s = 128; s > 0; s >>= 1) { if (tid < s) red[tid] += red[tid + s]; __syncthreads(); }
    float inv = 1.f / red[0]; __syncthreads();

    {
        float s = 0.f;
        for (int l = lbeg; l < lend; ++l) s = fmaf(vb[l], attns[l], s);
        red[tid] = s * inv;
    }
    __syncthreads();
    if (tid < 64)
        zs[tid] = red[tid * 4] + red[tid * 4 + 1] + red[tid * 4 + 2] + red[tid * 4 + 3];
    __syncthreads();

    if (tid < LBL_) {
        float s = fc_b[tid];
        for (int hx = 0; hx < H_; ++hx) s = fmaf(zs[hx], fc_w[tid * H_ + hx], s);
        out[b * LBL_ + tid] = s;
    }
}

extern "C" void kernel_launch(void* const* d_in, const int* in_sizes, int n_in,
                              void* d_out, int out_size, void* d_ws, size_t ws_size,
                              hipStream_t stream)
{
    const float* x      = (const float*)d_in[0];
    const float* conv_w = (const float*)d_in[1];
    const float* conv_b = (const float*)d_in[2];
    const float* va_w1  = (const float*)d_in[3];
    const float* va_b1  = (const float*)d_in[4];
    const float* va_w2  = (const float*)d_in[5];
    const float* va_b2  = (const float*)d_in[6];
    const float* ta_w1  = (const float*)d_in[7];
    const float* ta_b1  = (const float*)d_in[8];
    const float* ta_w2  = (const float*)d_in[9];
    const float* ta_b2  = (const float*)d_in[10];
    const float* fc_w   = (const float*)d_in[11];
    const float* fc_b   = (const float*)d_in[12];

    float* ws    = (float*)d_ws;
    float* A     = ws;                      // 1728
    float* Abias = ws + 1728;               // 64
    float* aw    = ws + 2048;               // 32*8*84*64 = 1,376,256
    float* v     = ws + 2048 + 1376256;     // 32*64*510 = 1,044,480

    precomp_kernel<<<1, 256, 0, stream>>>(conv_w, conv_b, va_w1, va_b1, A, Abias);
    attn_kernel<<<dim3(8, B_), 1024, 0, stream>>>(x, va_w2, va_b2, A, Abias, aw);
    passB_kernel<<<dim3(8, B_, 8), 256, 0, stream>>>(x, conv_w, conv_b, aw, v);
    ta_kernel<<<B_, 256, 0, stream>>>(v, ta_w1, ta_b1, ta_w2, ta_b2, fc_w, fc_b, (float*)d_out);
}

// Round 4
// 125.314 us; speedup vs baseline: 3.4768x; 3.4768x over previous
//
#include <hip/hip_runtime.h>
#include <hip/hip_bf16.h>

#define B_ 32
#define T_ 512
#define F_ 9
#define H_ 64
#define P_ 84
#define LE_ 510
#define LBL_ 10

struct CombT { int c[P_][3]; };
__host__ __device__ constexpr CombT make_combs() {
    CombT t{}; int n = 0;
    for (int a = 0; a < F_; ++a)
        for (int b = a + 1; b < F_; ++b)
            for (int c = b + 1; c < F_; ++c) { t.c[n][0] = a; t.c[n][1] = b; t.c[n][2] = c; ++n; }
    return t;
}
constexpr CombT COMB_H = make_combs();
__device__ __constant__ CombT COMB = make_combs();   // runtime scalar loads

// ---------------------------------------------------------------------------
// Kernel A: A[h][f*3+k] = sum_p va_w1[p] * sum_i [comb[p][i]==f] w[p,h,i,k]
//           Abias[h]    = va_b1[h] + sum_p va_w1[p]*conv_b[p,h]
// ---------------------------------------------------------------------------
__global__ __launch_bounds__(256) void precomp_kernel(
    const float* __restrict__ conv_w, const float* __restrict__ conv_b,
    const float* __restrict__ va_w1, const float* __restrict__ va_b1,
    float* __restrict__ A, float* __restrict__ Abias)
{
    __shared__ float sacc[256][28];
    int tid = threadIdx.x;
    int h = tid >> 2, q = tid & 3;            // 64 h  x  4 p-quarters
    for (int j = 0; j < 28; ++j) sacc[tid][j] = 0.f;
    for (int p = q * 21; p < (q + 1) * 21; ++p) {
        float w1 = va_w1[p];
        sacc[tid][27] += w1 * conv_b[p * H_ + h];
        const float* wp = conv_w + p * (H_ * 9) + h * 9;
        for (int i = 0; i < 3; ++i) {
            int f = COMB_H.c[p][i];
            for (int k = 0; k < 3; ++k) sacc[tid][f * 3 + k] += w1 * wp[i * 3 + k];
        }
    }
    __syncthreads();
    if (q == 0) {
        for (int j = 0; j < 27; ++j)
            A[h * 27 + j] = sacc[tid][j] + sacc[tid + 1][j] + sacc[tid + 2][j] + sacc[tid + 3][j];
        Abias[h] = va_b1[h] + sacc[tid][27] + sacc[tid + 1][27] + sacc[tid + 2][27] + sacc[tid + 3][27];
    }
}

// ---------------------------------------------------------------------------
// attn_kernel: per (ltile, b), 1024 threads (16 waves), lane = l.
// t1 (via A) -> t2 -> softmax -> store aw[b,lt,p,l] (normalized weights).
// ---------------------------------------------------------------------------
__global__ __launch_bounds__(1024) void attn_kernel(
    const float* __restrict__ x,
    const float* __restrict__ va_w2, const float* __restrict__ va_b2,
    const float* __restrict__ A, const float* __restrict__ Abias,
    float* __restrict__ aw)
{
    __shared__ float xs[66 * 9];
    __shared__ float t1s[64][65];
    __shared__ float t2s[64][85];

    const int b = blockIdx.y;
    const int lt = blockIdx.x;
    const int l0 = lt * 64;
    const int tid = threadIdx.x;
    const int ln = tid & 63;
    const int wv = tid >> 6;            // 0..15

    int maxidx = (T_ - l0) * F_; if (maxidx > 66 * F_) maxidx = 66 * F_;
    for (int i = tid; i < 66 * F_; i += 1024)
        xs[i] = (i < maxidx) ? x[b * (T_ * F_) + l0 * F_ + i] : 0.f;
    __syncthreads();

    float xw[27];
#pragma unroll
    for (int k = 0; k < 3; ++k)
#pragma unroll
        for (int f = 0; f < F_; ++f) xw[k * 9 + f] = xs[(ln + k) * F_ + f];

    // t1: wave wv covers h = wv*4 .. wv*4+3
#pragma unroll
    for (int hh = 0; hh < 4; ++hh) {
        int h = wv * 4 + hh;
        const float* Ah = A + h * 27;
        float s = Abias[h];
#pragma unroll
        for (int f = 0; f < F_; ++f)
#pragma unroll
            for (int k = 0; k < 3; ++k) s = fmaf(xw[k * 9 + f], Ah[f * 3 + k], s);
        t1s[ln][h] = fmaxf(s, 0.f);
    }
    __syncthreads();

    // t2: wave wv covers a p-slice
    const int cnt = (wv < 4) ? 6 : 5;
    const int p0 = (wv < 4) ? wv * 6 : 24 + (wv - 4) * 5;
    {
        float t2acc[6];
#pragma unroll
        for (int j = 0; j < 6; ++j) t2acc[j] = (j < cnt) ? va_b2[p0 + j] : 0.f;
        for (int h = 0; h < H_; ++h) {
            float tv = t1s[ln][h];
            const float* w2h = va_w2 + h * P_ + p0;
#pragma unroll
            for (int j = 0; j < 6; ++j)
                if (j < cnt) t2acc[j] = fmaf(tv, w2h[j], t2acc[j]);
        }
#pragma unroll
        for (int j = 0; j < 6; ++j)
            if (j < cnt) t2s[ln][p0 + j] = fmaxf(t2acc[j], 0.f);
    }
    __syncthreads();

    float mx = -1e30f;
    for (int p = 0; p < P_; ++p) mx = fmaxf(mx, t2s[ln][p]);
    float sum = 0.f;
    for (int p = 0; p < P_; ++p) sum += __expf(t2s[ln][p] - mx);
    float inv = 1.f / sum;

    const int awbase = (b * 8 + lt) * P_;
#pragma unroll
    for (int j = 0; j < 6; ++j)
        if (j < cnt)
            aw[(awbase + p0 + j) * 64 + ln] = __expf(t2s[ln][p0 + j] - mx) * inv;
}

// ---------------------------------------------------------------------------
// passB_kernel: grid (lt 8, b 32, z 8), 256 thr (4 waves).
// Block covers h = z*8..z*8+7; the 4 waves SPLIT p (21 each) and cross-wave
// reduce in LDS.  x window lives in LDS as xpack[f][ln][k(pad4)] -> per-p
// gather = 3x ds_read_b128 at runtime f (no unroll needed, no spills).
// Weights: wave-uniform scalar loads (readfirstlane'd wave id).
// ---------------------------------------------------------------------------
__global__ __launch_bounds__(256, 4) void passB_kernel(
    const float* __restrict__ x,
    const float* __restrict__ conv_w, const float* __restrict__ conv_b,
    const float* __restrict__ aw,
    float* __restrict__ v)
{
    __shared__ float xraw[66 * 9];           // 2376 B
    __shared__ float xpack[9 * 64 * 4];      // 9216 B  [f][ln][k, pad 4]
    __shared__ float red[4][8][64];          // 8192 B  [wave][hh][ln]

    const int lt = blockIdx.x;
    const int b  = blockIdx.y;
    const int z  = blockIdx.z;
    const int l0 = lt * 64;
    const int tid = threadIdx.x;
    const int ln  = tid & 63;
    const int wv  = __builtin_amdgcn_readfirstlane(tid >> 6);   // 0..3, scalar

    // ---- stage raw x, then pack to [f][ln][k] ----
    int maxidx = (T_ - l0) * F_; if (maxidx > 66 * F_) maxidx = 66 * F_;
    for (int i = tid; i < 66 * F_; i += 256)
        xraw[i] = (i < maxidx) ? x[b * (T_ * F_) + l0 * F_ + i] : 0.f;
    __syncthreads();
    for (int i = tid; i < 9 * 64; i += 256) {
        int f = i >> 6, l = i & 63;
        xpack[i * 4 + 0] = xraw[(l + 0) * F_ + f];
        xpack[i * 4 + 1] = xraw[(l + 1) * F_ + f];
        xpack[i * 4 + 2] = xraw[(l + 2) * F_ + f];
        xpack[i * 4 + 3] = 0.f;
    }
    __syncthreads();

    const int p0 = wv * 21;
    float acc[8];
#pragma unroll
    for (int i = 0; i < 8; ++i) acc[i] = 0.f;

    const float* awp = aw + (((b * 8 + lt) * P_) + p0) * 64 + ln;
    const float* cw0 = conv_w + p0 * (H_ * 9) + z * 72;   // + pi*576 + hh*9
    const float* cb0 = conv_b + p0 * H_ + z * 8;          // + pi*64 + hh

#pragma unroll 3
    for (int pi = 0; pi < 21; ++pi) {
        const int p = p0 + pi;
        const int f0 = COMB.c[p][0];
        const int f1 = COMB.c[p][1];
        const int f2 = COMB.c[p][2];

        const float4 va = *reinterpret_cast<const float4*>(&xpack[(f0 * 64 + ln) * 4]);
        const float4 vb = *reinterpret_cast<const float4*>(&xpack[(f1 * 64 + ln) * 4]);
        const float4 vc = *reinterpret_cast<const float4*>(&xpack[(f2 * 64 + ln) * 4]);
        const float ap = awp[pi * 64];

        const float* wpp = cw0 + pi * (H_ * 9);
        const float* bpp = cb0 + pi * H_;
#pragma unroll
        for (int hh = 0; hh < 8; ++hh) {
            const float* w9 = wpp + hh * 9;       // uniform -> s_load
            float cv = bpp[hh];
            cv = fmaf(w9[0], va.x, cv);
            cv = fmaf(w9[1], va.y, cv);
            cv = fmaf(w9[2], va.z, cv);
            cv = fmaf(w9[3], vb.x, cv);
            cv = fmaf(w9[4], vb.y, cv);
            cv = fmaf(w9[5], vb.z, cv);
            cv = fmaf(w9[6], vc.x, cv);
            cv = fmaf(w9[7], vc.y, cv);
            cv = fmaf(w9[8], vc.z, cv);
            acc[hh] = fmaf(ap, cv, acc[hh]);
        }
    }

    // ---- cross-wave reduction ----
#pragma unroll
    for (int hh = 0; hh < 8; ++hh) red[wv][hh][ln] = acc[hh];
    __syncthreads();

    int valid = LE_ - l0; if (valid > 64) valid = 64;
    if (ln < valid) {
#pragma unroll
        for (int u = 0; u < 2; ++u) {
            const int hh = wv * 2 + u;
            float s = red[0][hh][ln] + red[1][hh][ln] + red[2][hh][ln] + red[3][hh][ln];
            v[(b * H_ + z * 8 + hh) * LE_ + l0 + ln] = s;
        }
    }
}

// ---------------------------------------------------------------------------
// Kernel 2: temporal attention + FC.  one block per b.
// ---------------------------------------------------------------------------
__global__ __launch_bounds__(256) void ta_kernel(
    const float* __restrict__ v,
    const float* __restrict__ ta_w1, const float* __restrict__ ta_b1,
    const float* __restrict__ ta_w2, const float* __restrict__ ta_b2,
    const float* __restrict__ fc_w, const float* __restrict__ fc_b,
    float* __restrict__ out)
{
    __shared__ float u1s[64];
    __shared__ float attns[512];
    __shared__ float red[256];
    __shared__ float zs[64];

    const int b = blockIdx.x;
    const int tid = threadIdx.x;
    const int h = tid >> 2, q = tid & 3;
    const int lbeg = q * 128;
    const int lend = (lbeg + 128 < LE_) ? lbeg + 128 : LE_;
    const float* vb = v + (b * H_ + h) * LE_;

    {
        float s = 0.f;
        for (int l = lbeg; l < lend; ++l) s = fmaf(vb[l], ta_w1[l], s);
        red[tid] = s;
    }
    __syncthreads();
    if (tid < 64)
        u1s[tid] = fmaxf(ta_b1[tid] + red[tid * 4] + red[tid * 4 + 1] + red[tid * 4 + 2] + red[tid * 4 + 3], 0.f);
    __syncthreads();

    for (int l = tid; l < LE_; l += 256) {
        float s = ta_b2[l];
        for (int hx = 0; hx < H_; ++hx) s = fmaf(u1s[hx], ta_w2[hx * LE_ + l], s);
        attns[l] = fmaxf(s, 0.f);
    }
    __syncthreads();

    float m = -1e30f;
    for (int l = tid; l < LE_; l += 256) m = fmaxf(m, attns[l]);
    red[tid] = m; __syncthreads();
    for (int s = 128; s > 0; s >>= 1) { if (tid < s) red[tid] = fmaxf(red[tid], red[tid + s]); __syncthreads(); }
    m = red[0]; __syncthreads();

    float ssum = 0.f;
    for (int l = tid; l < LE_; l += 256) { float e = __expf(attns[l] - m); attns[l] = e; ssum += e; }
    red[tid] = ssum; __syncthreads();
    for (int s = 128; s > 0; s >>= 1) { if (tid < s) red[tid] += red[tid + s]; __syncthreads(); }
    float inv = 1.f / red[0]; __syncthreads();

    {
        float s = 0.f;
        for (int l = lbeg; l < lend; ++l) s = fmaf(vb[l], attns[l], s);
        red[tid] = s * inv;
    }
    __syncthreads();
    if (tid < 64)
        zs[tid] = red[tid * 4] + red[tid * 4 + 1] + red[tid * 4 + 2] + red[tid * 4 + 3];
    __syncthreads();

    if (tid < LBL_) {
        float s = fc_b[tid];
        for (int hx = 0; hx < H_; ++hx) s = fmaf(zs[hx], fc_w[tid * H_ + hx], s);
        out[b * LBL_ + tid] = s;
    }
}

extern "C" void kernel_launch(void* const* d_in, const int* in_sizes, int n_in,
                              void* d_out, int out_size, void* d_ws, size_t ws_size,
                              hipStream_t stream)
{
    const float* x      = (const float*)d_in[0];
    const float* conv_w = (const float*)d_in[1];
    const float* conv_b = (const float*)d_in[2];
    const float* va_w1  = (const float*)d_in[3];
    const float* va_b1  = (const float*)d_in[4];
    const float* va_w2  = (const float*)d_in[5];
    const float* va_b2  = (const float*)d_in[6];
    const float* ta_w1  = (const float*)d_in[7];
    const float* ta_b1  = (const float*)d_in[8];
    const float* ta_w2  = (const float*)d_in[9];
    const float* ta_b2  = (const float*)d_in[10];
    const float* fc_w   = (const float*)d_in[11];
    const float* fc_b   = (const float*)d_in[12];

    float* ws    = (float*)d_ws;
    float* A     = ws;                      // 1728
    float* Abias = ws + 1728;               // 64
    float* aw    = ws + 2048;               // 32*8*84*64 = 1,376,256
    float* v     = ws + 2048 + 1376256;     // 32*64*510 = 1,044,480

    precomp_kernel<<<1, 256, 0, stream>>>(conv_w, conv_b, va_w1, va_b1, A, Abias);
    attn_kernel<<<dim3(8, B_), 1024, 0, stream>>>(x, va_w2, va_b2, A, Abias, aw);
    passB_kernel<<<dim3(8, B_, 8), 256, 0, stream>>>(x, conv_w, conv_b, aw, v);
    ta_kernel<<<B_, 256, 0, stream>>>(v, ta_w1, ta_b1, ta_w2, ta_b2, fc_w, fc_b, (float*)d_out);
}

// Round 5
// 86.232 us; speedup vs baseline: 5.0526x; 1.4532x over previous
//
#include <hip/hip_runtime.h>
#include <hip/hip_bf16.h>

#define B_ 32
#define T_ 512
#define F_ 9
#define H_ 64
#define P_ 84
#define LE_ 510
#define LBL_ 10

struct CombT { int c[P_][3]; };
__host__ __device__ constexpr CombT make_combs() {
    CombT t{}; int n = 0;
    for (int a = 0; a < F_; ++a)
        for (int b = a + 1; b < F_; ++b)
            for (int c = b + 1; c < F_; ++c) { t.c[n][0] = a; t.c[n][1] = b; t.c[n][2] = c; ++n; }
    return t;
}
constexpr CombT COMB_H = make_combs();
__device__ __constant__ CombT COMB = make_combs();   // runtime scalar loads

// ---------------------------------------------------------------------------
// Kernel A: A[h][f*3+k] = sum_p va_w1[p] * sum_i [comb[p][i]==f] w[p,h,i,k]
//           Abias[h]    = va_b1[h] + sum_p va_w1[p]*conv_b[p,h]
// ---------------------------------------------------------------------------
__global__ __launch_bounds__(256) void precomp_kernel(
    const float* __restrict__ conv_w, const float* __restrict__ conv_b,
    const float* __restrict__ va_w1, const float* __restrict__ va_b1,
    float* __restrict__ A, float* __restrict__ Abias)
{
    __shared__ float sacc[256][28];
    int tid = threadIdx.x;
    int h = tid >> 2, q = tid & 3;            // 64 h  x  4 p-quarters
    for (int j = 0; j < 28; ++j) sacc[tid][j] = 0.f;
    for (int p = q * 21; p < (q + 1) * 21; ++p) {
        float w1 = va_w1[p];
        sacc[tid][27] += w1 * conv_b[p * H_ + h];
        const float* wp = conv_w + p * (H_ * 9) + h * 9;
        for (int i = 0; i < 3; ++i) {
            int f = COMB_H.c[p][i];
            for (int k = 0; k < 3; ++k) sacc[tid][f * 3 + k] += w1 * wp[i * 3 + k];
        }
    }
    __syncthreads();
    if (q == 0) {
        for (int j = 0; j < 27; ++j)
            A[h * 27 + j] = sacc[tid][j] + sacc[tid + 1][j] + sacc[tid + 2][j] + sacc[tid + 3][j];
        Abias[h] = va_b1[h] + sacc[tid][27] + sacc[tid + 1][27] + sacc[tid + 2][27] + sacc[tid + 3][27];
    }
}

// ---------------------------------------------------------------------------
// attn_kernel: per (ltile, b), 1024 threads (16 waves), lane = l.
// t1 (via A) -> t2 -> softmax -> store aw[b,lt,p,l] (normalized weights).
// ---------------------------------------------------------------------------
__global__ __launch_bounds__(1024) void attn_kernel(
    const float* __restrict__ x,
    const float* __restrict__ va_w2, const float* __restrict__ va_b2,
    const float* __restrict__ A, const float* __restrict__ Abias,
    float* __restrict__ aw)
{
    __shared__ float xs[66 * 9];
    __shared__ float t1s[64][65];
    __shared__ float t2s[64][85];

    const int b = blockIdx.y;
    const int lt = blockIdx.x;
    const int l0 = lt * 64;
    const int tid = threadIdx.x;
    const int ln = tid & 63;
    const int wv = tid >> 6;            // 0..15

    int maxidx = (T_ - l0) * F_; if (maxidx > 66 * F_) maxidx = 66 * F_;
    for (int i = tid; i < 66 * F_; i += 1024)
        xs[i] = (i < maxidx) ? x[b * (T_ * F_) + l0 * F_ + i] : 0.f;
    __syncthreads();

    float xw[27];
#pragma unroll
    for (int k = 0; k < 3; ++k)
#pragma unroll
        for (int f = 0; f < F_; ++f) xw[k * 9 + f] = xs[(ln + k) * F_ + f];

    // t1: wave wv covers h = wv*4 .. wv*4+3
#pragma unroll
    for (int hh = 0; hh < 4; ++hh) {
        int h = wv * 4 + hh;
        const float* Ah = A + h * 27;
        float s = Abias[h];
#pragma unroll
        for (int f = 0; f < F_; ++f)
#pragma unroll
            for (int k = 0; k < 3; ++k) s = fmaf(xw[k * 9 + f], Ah[f * 3 + k], s);
        t1s[ln][h] = fmaxf(s, 0.f);
    }
    __syncthreads();

    // t2: wave wv covers a p-slice
    const int cnt = (wv < 4) ? 6 : 5;
    const int p0 = (wv < 4) ? wv * 6 : 24 + (wv - 4) * 5;
    {
        float t2acc[6];
#pragma unroll
        for (int j = 0; j < 6; ++j) t2acc[j] = (j < cnt) ? va_b2[p0 + j] : 0.f;
        for (int h = 0; h < H_; ++h) {
            float tv = t1s[ln][h];
            const float* w2h = va_w2 + h * P_ + p0;
#pragma unroll
            for (int j = 0; j < 6; ++j)
                if (j < cnt) t2acc[j] = fmaf(tv, w2h[j], t2acc[j]);
        }
#pragma unroll
        for (int j = 0; j < 6; ++j)
            if (j < cnt) t2s[ln][p0 + j] = fmaxf(t2acc[j], 0.f);
    }
    __syncthreads();

    float mx = -1e30f;
    for (int p = 0; p < P_; ++p) mx = fmaxf(mx, t2s[ln][p]);
    float sum = 0.f;
    for (int p = 0; p < P_; ++p) sum += __expf(t2s[ln][p] - mx);
    float inv = 1.f / sum;

    const int awbase = (b * 8 + lt) * P_;
#pragma unroll
    for (int j = 0; j < 6; ++j)
        if (j < cnt)
            aw[(awbase + p0 + j) * 64 + ln] = __expf(t2s[ln][p0 + j] - mx) * inv;
}

// ---------------------------------------------------------------------------
// passB_kernel: grid (lt 8, b 32, z 8), 256 thr (4 waves).
// Block covers h = z*8..z*8+7; the 4 waves SPLIT p (21 each) and cross-wave
// reduce in LDS.  x window lives in LDS as xpack[f][ln][k(pad4)] -> per-p
// gather = 3x ds_read_b128 at runtime f (no unroll needed, no spills).
// Weights: wave-uniform scalar loads (readfirstlane'd wave id).
// ---------------------------------------------------------------------------
__global__ __launch_bounds__(256, 4) void passB_kernel(
    const float* __restrict__ x,
    const float* __restrict__ conv_w, const float* __restrict__ conv_b,
    const float* __restrict__ aw,
    float* __restrict__ v)
{
    __shared__ float xraw[66 * 9];           // 2376 B
    __shared__ float xpack[9 * 64 * 4];      // 9216 B  [f][ln][k, pad 4]
    __shared__ float red[4][8][64];          // 8192 B  [wave][hh][ln]

    const int lt = blockIdx.x;
    const int b  = blockIdx.y;
    const int z  = blockIdx.z;
    const int l0 = lt * 64;
    const int tid = threadIdx.x;
    const int ln  = tid & 63;
    const int wv  = __builtin_amdgcn_readfirstlane(tid >> 6);   // 0..3, scalar

    // ---- stage raw x, then pack to [f][ln][k] ----
    int maxidx = (T_ - l0) * F_; if (maxidx > 66 * F_) maxidx = 66 * F_;
    for (int i = tid; i < 66 * F_; i += 256)
        xraw[i] = (i < maxidx) ? x[b * (T_ * F_) + l0 * F_ + i] : 0.f;
    __syncthreads();
    for (int i = tid; i < 9 * 64; i += 256) {
        int f = i >> 6, l = i & 63;
        xpack[i * 4 + 0] = xraw[(l + 0) * F_ + f];
        xpack[i * 4 + 1] = xraw[(l + 1) * F_ + f];
        xpack[i * 4 + 2] = xraw[(l + 2) * F_ + f];
        xpack[i * 4 + 3] = 0.f;
    }
    __syncthreads();

    const int p0 = wv * 21;
    float acc[8];
#pragma unroll
    for (int i = 0; i < 8; ++i) acc[i] = 0.f;

    const float* awp = aw + (((b * 8 + lt) * P_) + p0) * 64 + ln;
    const float* cw0 = conv_w + p0 * (H_ * 9) + z * 72;   // + pi*576 + hh*9
    const float* cb0 = conv_b + p0 * H_ + z * 8;          // + pi*64 + hh

#pragma unroll 3
    for (int pi = 0; pi < 21; ++pi) {
        const int p = p0 + pi;
        const int f0 = COMB.c[p][0];
        const int f1 = COMB.c[p][1];
        const int f2 = COMB.c[p][2];

        const float4 va = *reinterpret_cast<const float4*>(&xpack[(f0 * 64 + ln) * 4]);
        const float4 vb = *reinterpret_cast<const float4*>(&xpack[(f1 * 64 + ln) * 4]);
        const float4 vc = *reinterpret_cast<const float4*>(&xpack[(f2 * 64 + ln) * 4]);
        const float ap = awp[pi * 64];

        const float* wpp = cw0 + pi * (H_ * 9);
        const float* bpp = cb0 + pi * H_;
#pragma unroll
        for (int hh = 0; hh < 8; ++hh) {
            const float* w9 = wpp + hh * 9;       // uniform -> s_load
            float cv = bpp[hh];
            cv = fmaf(w9[0], va.x, cv);
            cv = fmaf(w9[1], va.y, cv);
            cv = fmaf(w9[2], va.z, cv);
            cv = fmaf(w9[3], vb.x, cv);
            cv = fmaf(w9[4], vb.y, cv);
            cv = fmaf(w9[5], vb.z, cv);
            cv = fmaf(w9[6], vc.x, cv);
            cv = fmaf(w9[7], vc.y, cv);
            cv = fmaf(w9[8], vc.z, cv);
            acc[hh] = fmaf(ap, cv, acc[hh]);
        }
    }

    // ---- cross-wave reduction ----
#pragma unroll
    for (int hh = 0; hh < 8; ++hh) red[wv][hh][ln] = acc[hh];
    __syncthreads();

    int valid = LE_ - l0; if (valid > 64) valid = 64;
    if (ln < valid) {
#pragma unroll
        for (int u = 0; u < 2; ++u) {
            const int hh = wv * 2 + u;
            float s = red[0][hh][ln] + red[1][hh][ln] + red[2][hh][ln] + red[3][hh][ln];
            v[(b * H_ + z * 8 + hh) * LE_ + l0 + ln] = s;
        }
    }
}

// ---------------------------------------------------------------------------
// ta_kernel v2: one block per b, 512 threads (8 waves).
// All phases coalesced:
//  u1: wave wv -> h = wv*8..wv*8+7, lanes stride l; butterfly reduce.
//  u2: thread = l (coalesced ta_w2), u1 broadcast from LDS.
//  softmax: wave shuffle + 8-entry cross-wave reduce.
//  z : same shape as u1 with attn weights.  FC: first 10 threads.
// ---------------------------------------------------------------------------
__global__ __launch_bounds__(512) void ta_kernel(
    const float* __restrict__ v,
    const float* __restrict__ ta_w1, const float* __restrict__ ta_b1,
    const float* __restrict__ ta_w2, const float* __restrict__ ta_b2,
    const float* __restrict__ fc_w, const float* __restrict__ fc_b,
    float* __restrict__ out)
{
    __shared__ float u1s[64];
    __shared__ float attns[512];
    __shared__ float red8[8];
    __shared__ float zs[64];

    const int b = blockIdx.x;
    const int tid = threadIdx.x;
    const int ln = tid & 63;
    const int wv = tid >> 6;             // 0..7
    const float* vb = v + b * (H_ * LE_);

    // ---- u1[h] : wave wv covers h = wv*8 .. wv*8+7 ----
#pragma unroll
    for (int hh = 0; hh < 8; ++hh) {
        const int h = wv * 8 + hh;
        const float* row = vb + h * LE_;
        float s = 0.f;
#pragma unroll
        for (int it = 0; it < 8; ++it) {
            int l = it * 64 + ln;
            if (l < LE_) s = fmaf(row[l], ta_w1[l], s);
        }
#pragma unroll
        for (int off = 32; off > 0; off >>= 1) s += __shfl_xor(s, off);
        if (ln == 0) u1s[h] = fmaxf(s + ta_b1[h], 0.f);
    }
    __syncthreads();

    // ---- u2[l] : thread = l, coalesced ta_w2 reads ----
    float val = -1e30f;
    if (tid < LE_) {
        float s0 = ta_b2[tid], s1 = 0.f, s2 = 0.f, s3 = 0.f;
#pragma unroll
        for (int h = 0; h < H_; h += 4) {
            s0 = fmaf(u1s[h + 0], ta_w2[(h + 0) * LE_ + tid], s0);
            s1 = fmaf(u1s[h + 1], ta_w2[(h + 1) * LE_ + tid], s1);
            s2 = fmaf(u1s[h + 2], ta_w2[(h + 2) * LE_ + tid], s2);
            s3 = fmaf(u1s[h + 3], ta_w2[(h + 3) * LE_ + tid], s3);
        }
        val = fmaxf((s0 + s1) + (s2 + s3), 0.f);
    }

    // ---- softmax over l (block-wide) ----
    float m = val;
#pragma unroll
    for (int off = 32; off > 0; off >>= 1) m = fmaxf(m, __shfl_xor(m, off));
    if (ln == 0) red8[wv] = m;
    __syncthreads();
    float M = red8[0];
#pragma unroll
    for (int i = 1; i < 8; ++i) M = fmaxf(M, red8[i]);

    float e = (tid < LE_) ? __expf(val - M) : 0.f;
    float s = e;
#pragma unroll
    for (int off = 32; off > 0; off >>= 1) s += __shfl_xor(s, off);
    __syncthreads();                 // red8 reuse
    if (ln == 0) red8[wv] = s;
    __syncthreads();
    float S = red8[0];
#pragma unroll
    for (int i = 1; i < 8; ++i) S += red8[i];
    attns[tid] = e * (1.f / S);
    __syncthreads();

    // ---- z[h] : same shape as u1 with attn weights ----
#pragma unroll
    for (int hh = 0; hh < 8; ++hh) {
        const int h = wv * 8 + hh;
        const float* row = vb + h * LE_;
        float t = 0.f;
#pragma unroll
        for (int it = 0; it < 8; ++it) {
            int l = it * 64 + ln;
            if (l < LE_) t = fmaf(row[l], attns[l], t);
        }
#pragma unroll
        for (int off = 32; off > 0; off >>= 1) t += __shfl_xor(t, off);
        if (ln == 0) zs[h] = t;
    }
    __syncthreads();

    // ---- FC ----
    if (tid < LBL_) {
        float r = fc_b[tid];
#pragma unroll
        for (int h = 0; h < H_; ++h) r = fmaf(zs[h], fc_w[tid * H_ + h], r);
        out[b * LBL_ + tid] = r;
    }
}

extern "C" void kernel_launch(void* const* d_in, const int* in_sizes, int n_in,
                              void* d_out, int out_size, void* d_ws, size_t ws_size,
                              hipStream_t stream)
{
    const float* x      = (const float*)d_in[0];
    const float* conv_w = (const float*)d_in[1];
    const float* conv_b = (const float*)d_in[2];
    const float* va_w1  = (const float*)d_in[3];
    const float* va_b1  = (const float*)d_in[4];
    const float* va_w2  = (const float*)d_in[5];
    const float* va_b2  = (const float*)d_in[6];
    const float* ta_w1  = (const float*)d_in[7];
    const float* ta_b1  = (const float*)d_in[8];
    const float* ta_w2  = (const float*)d_in[9];
    const float* ta_b2  = (const float*)d_in[10];
    const float* fc_w   = (const float*)d_in[11];
    const float* fc_b   = (const float*)d_in[12];

    float* ws    = (float*)d_ws;
    float* A     = ws;                      // 1728
    float* Abias = ws + 1728;               // 64
    float* aw    = ws + 2048;               // 32*8*84*64 = 1,376,256
    float* v     = ws + 2048 + 1376256;     // 32*64*510 = 1,044,480

    precomp_kernel<<<1, 256, 0, stream>>>(conv_w, conv_b, va_w1, va_b1, A, Abias);
    attn_kernel<<<dim3(8, B_), 1024, 0, stream>>>(x, va_w2, va_b2, A, Abias, aw);
    passB_kernel<<<dim3(8, B_, 8), 256, 0, stream>>>(x, conv_w, conv_b, aw, v);
    ta_kernel<<<B_, 512, 0, stream>>>(v, ta_w1, ta_b1, ta_w2, ta_b2, fc_w, fc_b, (float*)d_out);
}